// Round 1
// baseline (301.178 us; speedup 1.0000x reference)
//
#include <hip/hip_runtime.h>
#include <math.h>

#define BB 8
#define CC 64
#define OO 64
#define HH 128
#define WW 128
#define PP 9
#define HWW (HH*WW)

// ---------------------------------------------------------------------------
// Kernel 1: h = SiLU(BN(DWConv3x3(x) + dw_b)), NCHW, pad=1
// ---------------------------------------------------------------------------
__global__ void k_dwconv(const float* __restrict__ x,
                         const float* __restrict__ dw_w,
                         const float* __restrict__ dw_b,
                         const float* __restrict__ gamma,
                         const float* __restrict__ beta,
                         const float* __restrict__ mean,
                         const float* __restrict__ var,
                         float* __restrict__ h) {
  int idx = blockIdx.x * blockDim.x + threadIdx.x;
  if (idx >= BB * CC * HWW) return;
  int xw = idx % WW;
  int y  = (idx / WW) % HH;
  int c  = (idx / HWW) % CC;
  int b  = idx / (CC * HWW);
  const float* xp = x + (size_t)(b * CC + c) * HWW;
  const float* wp = dw_w + c * 9;
  float s = 0.f;
  #pragma unroll
  for (int dy = -1; dy <= 1; ++dy) {
    int yy = y + dy;
    if (yy < 0 || yy >= HH) continue;
    #pragma unroll
    for (int dx = -1; dx <= 1; ++dx) {
      int xx = xw + dx;
      if (xx < 0 || xx >= WW) continue;
      s += xp[yy * WW + xx] * wp[(dy + 1) * 3 + (dx + 1)];
    }
  }
  s += dw_b[c];
  float inv = rsqrtf(var[c] + 1e-5f);
  float t = (s - mean[c]) * (gamma[c] * inv) + beta[c];
  float sig = 1.f / (1.f + expf(-t));
  h[idx] = t * sig;
}

// ---------------------------------------------------------------------------
// Kernel 2: 1x1 conv over h -> 18 offsets per pixel -> sample coords (sy,sx)
// soff layout: (B*HW, P, 2)
// ---------------------------------------------------------------------------
__global__ void k_offsets(const float* __restrict__ h,
                          const float* __restrict__ pw_w,
                          const float* __restrict__ pw_b,
                          float* __restrict__ soff) {
  int idx = blockIdx.x * blockDim.x + threadIdx.x;
  if (idx >= BB * HWW) return;
  int n = idx % HWW;
  int b = idx / HWW;
  int y = n / WW, xw = n % WW;
  float off[2 * PP];
  #pragma unroll
  for (int k = 0; k < 2 * PP; ++k) off[k] = pw_b[k];
  const float* hp = h + (size_t)b * CC * HWW + n;
  for (int c = 0; c < CC; ++c) {
    float hv = hp[(size_t)c * HWW];
    #pragma unroll
    for (int k = 0; k < 2 * PP; ++k) off[k] += pw_w[k * CC + c] * hv;
  }
  float* op = soff + (size_t)idx * PP * 2;
  #pragma unroll
  for (int p = 0; p < PP; ++p) {
    // initial offsets: grid g=3, center 1 -> (p/3 - 1, p%3 - 1), DILATION=1
    float iy = (float)(p / 3 - 1);
    float ix = (float)(p % 3 - 1);
    op[p * 2 + 0] = (float)y  + off[2 * p + 0] + iy;
    op[p * 2 + 1] = (float)xw + off[2 * p + 1] + ix;
  }
}

// ---------------------------------------------------------------------------
// Kernel 3: transpose weight (O,C,P) -> wt[(c*P+p)*O + o]
// ---------------------------------------------------------------------------
__global__ void k_wt(const float* __restrict__ w, float* __restrict__ wt) {
  int i = blockIdx.x * blockDim.x + threadIdx.x;
  if (i >= OO * CC * PP) return;
  int p = i % PP;
  int c = (i / PP) % CC;
  int o = i / (CC * PP);
  wt[(c * PP + p) * OO + o] = w[i];
}

// ---------------------------------------------------------------------------
// Kernel 4: main — per-pixel bilinear gather + (c,p)-contraction into 64 outs
// One thread per (b, n) pixel; coalesced stores (n fastest within block).
// ---------------------------------------------------------------------------
__global__ void __launch_bounds__(256)
k_main(const float* __restrict__ x,
       const float* __restrict__ soff,
       const float* __restrict__ wt,
       const float* __restrict__ bias,
       float* __restrict__ out) {
  int idx = blockIdx.x * blockDim.x + threadIdx.x;
  if (idx >= BB * HWW) return;
  int n = idx % HWW;
  int b = idx / HWW;

  float acc[OO];
  #pragma unroll
  for (int o = 0; o < OO; ++o) acc[o] = bias[o];

  const float* xb = x + (size_t)b * CC * HWW;
  const float* op = soff + (size_t)idx * PP * 2;

  for (int p = 0; p < PP; ++p) {
    float sy = op[2 * p + 0];
    float sx = op[2 * p + 1];
    float y0f = floorf(sy), x0f = floorf(sx);
    float wy1 = sy - y0f, wy0 = 1.f - wy1;
    float wx1 = sx - x0f, wx0 = 1.f - wx1;
    int y0 = (int)y0f, x0 = (int)x0f;
    int y1 = y0 + 1, x1 = x0 + 1;
    bool vy0 = (y0 >= 0) & (y0 < HH);
    bool vy1 = (y1 >= 0) & (y1 < HH);
    bool vx0 = (x0 >= 0) & (x0 < WW);
    bool vx1 = (x1 >= 0) & (x1 < WW);
    int yc0 = min(max(y0, 0), HH - 1), yc1 = min(max(y1, 0), HH - 1);
    int xc0 = min(max(x0, 0), WW - 1), xc1 = min(max(x1, 0), WW - 1);
    float w00 = (vy0 && vx0) ? wy0 * wx0 : 0.f;
    float w01 = (vy0 && vx1) ? wy0 * wx1 : 0.f;
    float w10 = (vy1 && vx0) ? wy1 * wx0 : 0.f;
    float w11 = (vy1 && vx1) ? wy1 * wx1 : 0.f;
    int i00 = yc0 * WW + xc0, i01 = yc0 * WW + xc1;
    int i10 = yc1 * WW + xc0, i11 = yc1 * WW + xc1;

    for (int c = 0; c < CC; ++c) {
      const float* xc = xb + (size_t)c * HWW;
      float v = w00 * xc[i00] + w01 * xc[i01] + w10 * xc[i10] + w11 * xc[i11];
      const float* wp = wt + (size_t)(c * PP + p) * OO;
      #pragma unroll
      for (int o = 0; o < OO; o += 4) {
        float4 wv = *reinterpret_cast<const float4*>(wp + o);
        acc[o + 0] += v * wv.x;
        acc[o + 1] += v * wv.y;
        acc[o + 2] += v * wv.z;
        acc[o + 3] += v * wv.w;
      }
    }
  }

  float* outp = out + (size_t)b * OO * HWW + n;
  #pragma unroll
  for (int o = 0; o < OO; ++o) outp[(size_t)o * HWW] = acc[o];
}

// ---------------------------------------------------------------------------
extern "C" void kernel_launch(void* const* d_in, const int* in_sizes, int n_in,
                              void* d_out, int out_size, void* d_ws, size_t ws_size,
                              hipStream_t stream) {
  const float* x        = (const float*)d_in[0];
  const float* dw_w     = (const float*)d_in[1];
  const float* dw_b     = (const float*)d_in[2];
  const float* bn_gamma = (const float*)d_in[3];
  const float* bn_beta  = (const float*)d_in[4];
  const float* bn_mean  = (const float*)d_in[5];
  const float* bn_var   = (const float*)d_in[6];
  const float* pw_w     = (const float*)d_in[7];
  const float* pw_b     = (const float*)d_in[8];
  const float* weight   = (const float*)d_in[9];
  const float* bias     = (const float*)d_in[10];
  float* out = (float*)d_out;

  // workspace layout
  char* ws = (char*)d_ws;
  float* h    = (float*)ws;                                   // B*C*HW
  float* soff = (float*)(ws + (size_t)BB * CC * HWW * 4);     // B*HW*P*2
  float* wt   = (float*)(ws + (size_t)BB * CC * HWW * 4
                            + (size_t)BB * HWW * PP * 2 * 4); // C*P*O

  {
    int total = BB * CC * HWW;
    k_dwconv<<<(total + 255) / 256, 256, 0, stream>>>(
        x, dw_w, dw_b, bn_gamma, bn_beta, bn_mean, bn_var, h);
  }
  {
    int total = BB * HWW;
    k_offsets<<<(total + 255) / 256, 256, 0, stream>>>(h, pw_w, pw_b, soff);
  }
  {
    int total = OO * CC * PP;
    k_wt<<<(total + 255) / 256, 256, 0, stream>>>(weight, wt);
  }
  {
    int total = BB * HWW;
    k_main<<<(total + 255) / 256, 256, 0, stream>>>(x, soff, wt, bias, out);
  }
}

// Round 2
// 231.121 us; speedup vs baseline: 1.3031x; 1.3031x over previous
//
#include <hip/hip_runtime.h>
#include <math.h>

#define BB 8
#define CC 64
#define OO 64
#define HH 128
#define WW 128
#define PP 9
#define HWIMG 16384           // H*W per batch
#define NTOT  131072          // B*H*W

typedef __attribute__((ext_vector_type(8))) short short8;
typedef __attribute__((ext_vector_type(4))) float f32x4;

__device__ __forceinline__ unsigned short f2bf(float f) {
  unsigned u = __float_as_uint(f);
  u += 0x7fffu + ((u >> 16) & 1u);
  return (unsigned short)(u >> 16);
}

// ---------------------------------------------------------------------------
// Kernel 1: weight (O,C,P) f32 -> wtb[p][o][c] bf16   (A-matrix per K-chunk p)
// ---------------------------------------------------------------------------
__global__ void k_wt(const float* __restrict__ w, unsigned short* __restrict__ wtb) {
  int i = blockIdx.x * blockDim.x + threadIdx.x;
  if (i >= PP * OO * CC) return;
  int c = i & 63;
  int o = (i >> 6) & 63;
  int p = i >> 12;
  wtb[i] = f2bf(w[(o * 64 + c) * 9 + p]);
}

// ---------------------------------------------------------------------------
// Kernel 2: fused DWConv3x3 + BN + SiLU + 1x1 conv -> sample coords
// soff layout: plane-major soff[2p][n]=sy, soff[2p+1][n]=sx  (n in B*HW)
// ---------------------------------------------------------------------------
__global__ void k_off2(const float* __restrict__ x,
                       const float* __restrict__ dw_w,
                       const float* __restrict__ dw_b,
                       const float* __restrict__ gamma,
                       const float* __restrict__ beta,
                       const float* __restrict__ mean,
                       const float* __restrict__ var,
                       const float* __restrict__ pw_w,
                       const float* __restrict__ pw_b,
                       float* __restrict__ soff) {
  int bid = blockIdx.x;
  int vbid = (bid & 7) * 64 + (bid >> 3);   // 512 blocks -> XCD k gets batch k
  int idx = vbid * 256 + threadIdx.x;
  int b = idx >> 14;
  int n = idx & (HWIMG - 1);
  int y = n >> 7, xw = n & 127;

  float off[2 * PP];
  #pragma unroll
  for (int k = 0; k < 2 * PP; ++k) off[k] = pw_b[k];

  const float* xbb = x + (size_t)b * CC * HWIMG;
  #pragma unroll 1
  for (int c = 0; c < CC; ++c) {
    const float* xp = xbb + c * HWIMG;
    const float* wp = dw_w + c * 9;
    float s = 0.f;
    #pragma unroll
    for (int dy = 0; dy < 3; ++dy) {
      int yy = y + dy - 1;
      bool oky = (yy >= 0) && (yy < HH);
      int yyc = min(max(yy, 0), HH - 1);
      #pragma unroll
      for (int dx = 0; dx < 3; ++dx) {
        int xx = xw + dx - 1;
        bool ok = oky && (xx >= 0) && (xx < WW);
        int xxc = min(max(xx, 0), WW - 1);
        float xv = xp[yyc * WW + xxc];
        s += (ok ? xv : 0.f) * wp[dy * 3 + dx];
      }
    }
    s += dw_b[c];
    float t = (s - mean[c]) * (gamma[c] * rsqrtf(var[c] + 1e-5f)) + beta[c];
    float hs = t / (1.f + __expf(-t));          // t * sigmoid(t)
    #pragma unroll
    for (int k = 0; k < 2 * PP; ++k) off[k] += pw_w[k * CC + c] * hs;
  }

  float fy = (float)y, fx = (float)xw;
  #pragma unroll
  for (int p = 0; p < PP; ++p) {
    soff[(2 * p) * NTOT + idx]     = fy + off[2 * p]     + (float)(p / 3 - 1);
    soff[(2 * p + 1) * NTOT + idx] = fx + off[2 * p + 1] + (float)(p % 3 - 1);
  }
}

// ---------------------------------------------------------------------------
// Kernel 3: fused bilinear-gather + MFMA GEMM
//   C[o=64][n=128 per block] = sum_{p,c} W[o][c][p] * sampled[c][n;p]
//   Block = 128 pixels (one image row), 4 waves, 9 K-chunks (one per p).
//   B_lds[n][k] bf16, XOR-swizzled (T2): byte ^= ((n&7)<<4).
// ---------------------------------------------------------------------------
__global__ void __launch_bounds__(256, 4)
k_main(const float* __restrict__ x,
       const float* __restrict__ soff,
       const unsigned short* __restrict__ wtb,
       const float* __restrict__ bias,
       float* __restrict__ out) {
  __shared__ __attribute__((aligned(16))) char smem[128 * 128];

  int bid = blockIdx.x;
  int vbid = (bid & 7) * 128 + (bid >> 3);  // 1024 blocks -> XCD k gets batch k
  int tid = threadIdx.x;
  int wid = tid >> 6, ln = tid & 63;

  int b    = vbid >> 7;            // batch
  int pix0 = (vbid & 127) * 128;   // pixel base within batch (one row)
  int n0g  = vbid * 128;           // global pixel base

  const float* xb = x + (size_t)b * CC * HWIMG;

  int nl  = (wid >> 1) * 64 + ln;  // gather: pixel-in-block for this thread
  int cb0 = (wid & 1) * 32;        // gather: channel base for this thread
  int ng  = n0g + nl;

  f32x4 acc[4][2];
  #pragma unroll
  for (int mt = 0; mt < 4; ++mt)
    #pragma unroll
    for (int nt = 0; nt < 2; ++nt)
      acc[mt][nt] = (f32x4){0.f, 0.f, 0.f, 0.f};

  #pragma unroll 1
  for (int p = 0; p < PP; ++p) {
    if (p) __syncthreads();        // protect B_lds from previous chunk's reads

    // ---- per-chunk bilinear coords for (pixel ng, point p)
    float sy = soff[(2 * p) * NTOT + ng];
    float sx = soff[(2 * p + 1) * NTOT + ng];
    float y0f = floorf(sy), x0f = floorf(sx);
    float wy1 = sy - y0f, wy0 = 1.f - wy1;
    float wx1 = sx - x0f, wx0 = 1.f - wx1;
    int y0 = (int)y0f, x0 = (int)x0f;
    int y1 = y0 + 1, x1 = x0 + 1;
    bool vy0 = (y0 >= 0) & (y0 < HH);
    bool vy1 = (y1 >= 0) & (y1 < HH);
    bool vx0 = (x0 >= 0) & (x0 < WW);
    bool vx1 = (x1 >= 0) & (x1 < WW);
    int yc0 = min(max(y0, 0), HH - 1), yc1 = min(max(y1, 0), HH - 1);
    int xc0 = min(max(x0, 0), WW - 1), xc1 = min(max(x1, 0), WW - 1);
    float w00 = (vy0 && vx0) ? wy0 * wx0 : 0.f;
    float w01 = (vy0 && vx1) ? wy0 * wx1 : 0.f;
    float w10 = (vy1 && vx0) ? wy1 * wx0 : 0.f;
    float w11 = (vy1 && vx1) ? wy1 * wx1 : 0.f;
    int i00 = yc0 * WW + xc0, i01 = yc0 * WW + xc1;
    int i10 = yc1 * WW + xc0, i11 = yc1 * WW + xc1;

    // ---- gather this thread's 32 channel values -> swizzled LDS
    #pragma unroll
    for (int cbi = 0; cbi < 4; ++cbi) {
      int c8 = cb0 + cbi * 8;
      short8 val;
      #pragma unroll
      for (int e = 0; e < 8; ++e) {
        int cofs = (c8 + e) << 14;
        float v = w00 * xb[cofs + i00] + w01 * xb[cofs + i01]
                + w10 * xb[cofs + i10] + w11 * xb[cofs + i11];
        val[e] = (short)f2bf(v);
      }
      int waddr = nl * 128 + ((c8 * 2) ^ ((nl & 7) << 4));
      *(short8*)(smem + waddr) = val;
    }
    __syncthreads();

    // ---- MFMA: each wave computes C[64 x 32] slice, K=64 this chunk
    #pragma unroll
    for (int ks = 0; ks < 2; ++ks) {
      short8 bfr[2];
      #pragma unroll
      for (int nt = 0; nt < 2; ++nt) {
        int n = wid * 32 + nt * 16 + (ln & 15);
        int kb = ks * 64 + ((ln >> 4) << 4);
        bfr[nt] = *(const short8*)(smem + n * 128 + (kb ^ ((n & 7) << 4)));
      }
      #pragma unroll
      for (int mt = 0; mt < 4; ++mt) {
        const unsigned short* ap = wtb + p * 4096 + (mt * 16 + (ln & 15)) * 64
                                 + ks * 32 + (ln >> 4) * 8;
        short8 afr = *(const short8*)ap;
        #pragma unroll
        for (int nt = 0; nt < 2; ++nt)
          acc[mt][nt] = __builtin_amdgcn_mfma_f32_16x16x32_bf16(
              afr, bfr[nt], acc[mt][nt], 0, 0, 0);
      }
    }
  }

  // ---- epilogue: C/D layout col=lane&15 (n), row=(lane>>4)*4+reg (m)
  #pragma unroll
  for (int mt = 0; mt < 4; ++mt)
    #pragma unroll
    for (int nt = 0; nt < 2; ++nt) {
      int pixn = pix0 + wid * 32 + nt * 16 + (ln & 15);
      int mb = mt * 16 + ((ln >> 4) << 2);
      #pragma unroll
      for (int r = 0; r < 4; ++r) {
        int m = mb + r;
        out[((size_t)b * OO + m) * HWIMG + pixn] = acc[mt][nt][r] + bias[m];
      }
    }
}

// ---------------------------------------------------------------------------
extern "C" void kernel_launch(void* const* d_in, const int* in_sizes, int n_in,
                              void* d_out, int out_size, void* d_ws, size_t ws_size,
                              hipStream_t stream) {
  const float* x        = (const float*)d_in[0];
  const float* dw_w     = (const float*)d_in[1];
  const float* dw_b     = (const float*)d_in[2];
  const float* bn_gamma = (const float*)d_in[3];
  const float* bn_beta  = (const float*)d_in[4];
  const float* bn_mean  = (const float*)d_in[5];
  const float* bn_var   = (const float*)d_in[6];
  const float* pw_w     = (const float*)d_in[7];
  const float* pw_b     = (const float*)d_in[8];
  const float* weight   = (const float*)d_in[9];
  const float* bias     = (const float*)d_in[10];
  float* out = (float*)d_out;

  char* ws = (char*)d_ws;
  float* soff          = (float*)ws;                        // 18 * NTOT f32 = 9.44 MB
  unsigned short* wtb  = (unsigned short*)(ws + (size_t)2 * PP * NTOT * 4);

  k_wt<<<(PP * OO * CC + 255) / 256, 256, 0, stream>>>(weight, wtb);
  k_off2<<<NTOT / 256, 256, 0, stream>>>(x, dw_w, dw_b, bn_gamma, bn_beta,
                                         bn_mean, bn_var, pw_w, pw_b, soff);
  k_main<<<NTOT / 128, 256, 0, stream>>>(x, soff, wtb, bias, out);
}

// Round 3
// 143.492 us; speedup vs baseline: 2.0989x; 1.6107x over previous
//
#include <hip/hip_runtime.h>
#include <math.h>

#define BB 8
#define CC 64
#define OO 64
#define HH 128
#define WW 128
#define PP 9
#define HWIMG 16384           // H*W per batch
#define NTOT  131072          // B*H*W

typedef __attribute__((ext_vector_type(8))) _Float16 h8;
typedef __attribute__((ext_vector_type(2))) _Float16 h2;
typedef __attribute__((ext_vector_type(4))) float f32x4;

// ---------------------------------------------------------------------------
// Kernel 1: weight (O,C,P) f32 -> wtf[p][o][c] f16
// ---------------------------------------------------------------------------
__global__ void k_wt(const float* __restrict__ w, _Float16* __restrict__ wtf) {
  int i = blockIdx.x * blockDim.x + threadIdx.x;
  if (i >= PP * OO * CC) return;
  int c = i & 63;
  int o = (i >> 6) & 63;
  int p = i >> 12;
  wtf[i] = (_Float16)w[(o * 64 + c) * 9 + p];
}

// ---------------------------------------------------------------------------
// Kernel 2: x NCHW f32 -> xt[b][pix][c] f16 (NHWC), LDS tile transpose
// Block: 64 pixels x 64 channels.
// ---------------------------------------------------------------------------
__global__ void __launch_bounds__(256, 4)
k_tr(const float* __restrict__ x, _Float16* __restrict__ xt) {
  __shared__ _Float16 lt[64][66];
  int bid = blockIdx.x;
  int vbid = (bid & 7) * 256 + (bid >> 3);    // XCD k <- batch k
  int tid = threadIdx.x;
  int wid = tid >> 6, ln = tid & 63;
  int b = vbid >> 8;
  int pix0 = (vbid & 255) * 64;
  const float* xbb = x + (size_t)b * CC * HWIMG;

  #pragma unroll
  for (int i = 0; i < 8; ++i) {
    int c0 = (wid * 8 + i) * 2;
    float v0 = xbb[(size_t)c0 * HWIMG + pix0 + ln];
    float v1 = xbb[(size_t)(c0 + 1) * HWIMG + pix0 + ln];
    h2 hv;
    hv[0] = (_Float16)v0;
    hv[1] = (_Float16)v1;
    *(h2*)&lt[ln][c0] = hv;   // word = 33*ln + c0/2 -> conflict-free
  }
  __syncthreads();

  int pq = tid >> 2, q = tid & 3;   // pixel, channel-quarter
  h8 o0, o1;
  #pragma unroll
  for (int j = 0; j < 4; ++j) {
    h2 v = *(h2*)&lt[pq][q * 16 + 2 * j];
    o0[2 * j] = v[0];
    o0[2 * j + 1] = v[1];
  }
  #pragma unroll
  for (int j = 0; j < 4; ++j) {
    h2 v = *(h2*)&lt[pq][q * 16 + 8 + 2 * j];
    o1[2 * j] = v[0];
    o1[2 * j + 1] = v[1];
  }
  _Float16* op = xt + ((size_t)((b << 14) + pix0 + pq)) * 64 + q * 16;
  *(h8*)op = o0;
  *(h8*)(op + 8) = o1;
}

// ---------------------------------------------------------------------------
// Kernel 3: fused DWConv3x3 + BN + SiLU + 1x1 conv -> sample coords
// soff layout: plane-major soff[2p][n]=sy, soff[2p+1][n]=sx  (n in B*HW)
// ---------------------------------------------------------------------------
__global__ void k_off2(const float* __restrict__ x,
                       const float* __restrict__ dw_w,
                       const float* __restrict__ dw_b,
                       const float* __restrict__ gamma,
                       const float* __restrict__ beta,
                       const float* __restrict__ mean,
                       const float* __restrict__ var,
                       const float* __restrict__ pw_w,
                       const float* __restrict__ pw_b,
                       float* __restrict__ soff) {
  int bid = blockIdx.x;
  int vbid = (bid & 7) * 64 + (bid >> 3);   // XCD k <- batch k
  int idx = vbid * 256 + threadIdx.x;
  int b = idx >> 14;
  int n = idx & (HWIMG - 1);
  int y = n >> 7, xw = n & 127;

  float off[2 * PP];
  #pragma unroll
  for (int k = 0; k < 2 * PP; ++k) off[k] = pw_b[k];

  const float* xbb = x + (size_t)b * CC * HWIMG;
  #pragma unroll 1
  for (int c = 0; c < CC; ++c) {
    const float* xp = xbb + c * HWIMG;
    const float* wp = dw_w + c * 9;
    float s = 0.f;
    #pragma unroll
    for (int dy = 0; dy < 3; ++dy) {
      int yy = y + dy - 1;
      bool oky = (yy >= 0) && (yy < HH);
      int yyc = min(max(yy, 0), HH - 1);
      #pragma unroll
      for (int dx = 0; dx < 3; ++dx) {
        int xx = xw + dx - 1;
        bool ok = oky && (xx >= 0) && (xx < WW);
        int xxc = min(max(xx, 0), WW - 1);
        float xv = xp[yyc * WW + xxc];
        s += (ok ? xv : 0.f) * wp[dy * 3 + dx];
      }
    }
    s += dw_b[c];
    float t = (s - mean[c]) * (gamma[c] * rsqrtf(var[c] + 1e-5f)) + beta[c];
    float hs = t / (1.f + __expf(-t));          // t * sigmoid(t)
    #pragma unroll
    for (int k = 0; k < 2 * PP; ++k) off[k] += pw_w[k * CC + c] * hs;
  }

  float fy = (float)y, fx = (float)xw;
  #pragma unroll
  for (int p = 0; p < PP; ++p) {
    soff[(size_t)(2 * p) * NTOT + idx]     = fy + off[2 * p]     + (float)(p / 3 - 1);
    soff[(size_t)(2 * p + 1) * NTOT + idx] = fx + off[2 * p + 1] + (float)(p % 3 - 1);
  }
}

// ---------------------------------------------------------------------------
// Kernel 4: LDS-free fused gather + MFMA GEMM
//   Each lane gathers its OWN B-frag: pixel = ln&15 (per n-tile), k-slice =
//   (ln>>4)*8. 4 coalesced corner dwordx4 loads + pk f16 interp -> frag.
//   Wave: 32 pixels (2 n-tiles) x 64 outputs (4 m-tiles), K = 9p x 64c.
// ---------------------------------------------------------------------------
__global__ void __launch_bounds__(256, 4)
k_main(const _Float16* __restrict__ xt,
       const float* __restrict__ soff,
       const _Float16* __restrict__ wtf,
       const float* __restrict__ bias,
       float* __restrict__ out) {
  int bid = blockIdx.x;
  int vbid = (bid & 7) * 128 + (bid >> 3);   // XCD k <- batch k
  int tid = threadIdx.x;
  int wid = tid >> 6, ln = tid & 63;
  int lm = ln & 15, lk = ln >> 4;
  int b = vbid >> 7;
  int prow = (vbid & 127) * 128 + wid * 32;  // wave's pixel base in image

  const _Float16* xb = xt + (((size_t)b) << 14) * 64;

  f32x4 acc[4][2];
  #pragma unroll
  for (int mt = 0; mt < 4; ++mt)
    #pragma unroll
    for (int nt = 0; nt < 2; ++nt) acc[mt][nt] = (f32x4){0.f, 0.f, 0.f, 0.f};

  #pragma unroll 1
  for (int p = 0; p < PP; ++p) {
    h8 bfr[2][2];   // [nt][kc]
    #pragma unroll
    for (int nt = 0; nt < 2; ++nt) {
      int pix = prow + nt * 16 + lm;
      int ng = (b << 14) + pix;
      float sy = soff[(size_t)(2 * p) * NTOT + ng];
      float sx = soff[(size_t)(2 * p + 1) * NTOT + ng];
      float y0f = floorf(sy), x0f = floorf(sx);
      float wy1 = sy - y0f, wy0 = 1.f - wy1;
      float wx1 = sx - x0f, wx0 = 1.f - wx1;
      int y0 = (int)y0f, x0i = (int)x0f;
      int y1 = y0 + 1, x1i = x0i + 1;
      bool vy0 = (y0 >= 0) & (y0 < HH);
      bool vy1 = (y1 >= 0) & (y1 < HH);
      bool vx0 = (x0i >= 0) & (x0i < WW);
      bool vx1 = (x1i >= 0) & (x1i < WW);
      int yc0 = min(max(y0, 0), HH - 1), yc1 = min(max(y1, 0), HH - 1);
      int xc0 = min(max(x0i, 0), WW - 1), xc1 = min(max(x1i, 0), WW - 1);
      float w00 = (vy0 && vx0) ? wy0 * wx0 : 0.f;
      float w01 = (vy0 && vx1) ? wy0 * wx1 : 0.f;
      float w10 = (vy1 && vx0) ? wy1 * wx0 : 0.f;
      float w11 = (vy1 && vx1) ? wy1 * wx1 : 0.f;
      int i00 = yc0 * WW + xc0, i01 = yc0 * WW + xc1;
      int i10 = yc1 * WW + xc0, i11 = yc1 * WW + xc1;
      h8 w00v = (h8)(_Float16)w00;
      h8 w01v = (h8)(_Float16)w01;
      h8 w10v = (h8)(_Float16)w10;
      h8 w11v = (h8)(_Float16)w11;
      #pragma unroll
      for (int kc = 0; kc < 2; ++kc) {
        int kb = kc * 32 + lk * 8;
        h8 va = *(const h8*)(xb + (size_t)i00 * 64 + kb);
        h8 vb = *(const h8*)(xb + (size_t)i01 * 64 + kb);
        h8 vc = *(const h8*)(xb + (size_t)i10 * 64 + kb);
        h8 vd = *(const h8*)(xb + (size_t)i11 * 64 + kb);
        bfr[nt][kc] = va * w00v + vb * w01v + vc * w10v + vd * w11v;
      }
    }

    #pragma unroll
    for (int kc = 0; kc < 2; ++kc) {
      #pragma unroll
      for (int mt = 0; mt < 4; ++mt) {
        h8 afr = *(const h8*)(wtf + (size_t)(p * 64 + mt * 16 + lm) * 64
                              + kc * 32 + lk * 8);
        #pragma unroll
        for (int nt = 0; nt < 2; ++nt)
          acc[mt][nt] = __builtin_amdgcn_mfma_f32_16x16x32_f16(
              afr, bfr[nt][kc], acc[mt][nt], 0, 0, 0);
      }
    }
  }

  // epilogue: C/D layout col=lane&15 (pixel), row=(lane>>4)*4+reg (m)
  #pragma unroll
  for (int mt = 0; mt < 4; ++mt)
    #pragma unroll
    for (int nt = 0; nt < 2; ++nt) {
      int pix = prow + nt * 16 + lm;
      #pragma unroll
      for (int r = 0; r < 4; ++r) {
        int m = mt * 16 + lk * 4 + r;
        out[((size_t)b * OO + m) * HWIMG + pix] = acc[mt][nt][r] + bias[m];
      }
    }
}

// ---------------------------------------------------------------------------
extern "C" void kernel_launch(void* const* d_in, const int* in_sizes, int n_in,
                              void* d_out, int out_size, void* d_ws, size_t ws_size,
                              hipStream_t stream) {
  const float* x        = (const float*)d_in[0];
  const float* dw_w     = (const float*)d_in[1];
  const float* dw_b     = (const float*)d_in[2];
  const float* bn_gamma = (const float*)d_in[3];
  const float* bn_beta  = (const float*)d_in[4];
  const float* bn_mean  = (const float*)d_in[5];
  const float* bn_var   = (const float*)d_in[6];
  const float* pw_w     = (const float*)d_in[7];
  const float* pw_b     = (const float*)d_in[8];
  const float* weight   = (const float*)d_in[9];
  const float* bias     = (const float*)d_in[10];
  float* out = (float*)d_out;

  char* ws = (char*)d_ws;
  float* soff    = (float*)ws;                                  // 18*NTOT f32 = 9.44 MB
  _Float16* wtf  = (_Float16*)(ws + (size_t)2 * PP * NTOT * 4); // 72 KB f16
  _Float16* xtb  = (_Float16*)(ws + (size_t)2 * PP * NTOT * 4
                                  + (size_t)PP * OO * CC * 2);  // 16.8 MB f16

  k_wt<<<(PP * OO * CC + 255) / 256, 256, 0, stream>>>(weight, wtf);
  k_tr<<<NTOT / 64, 256, 0, stream>>>(x, xtb);
  k_off2<<<NTOT / 256, 256, 0, stream>>>(x, dw_w, dw_b, bn_gamma, bn_beta,
                                         bn_mean, bn_var, pw_w, pw_b, soff);
  k_main<<<NTOT / 128, 256, 0, stream>>>(xtb, soff, wtf, bias, out);
}